// Round 1
// baseline (80.064 us; speedup 1.0000x reference)
//
#include <hip/hip_runtime.h>
#include <hip/hip_bf16.h>

#define H 128
#define STEPS 64
#define F_IN 33

__global__ __launch_bounds__(H) void Encoder_57380763074770_kernel(
    const float* __restrict__ x,        // [64,17]
    const int*   __restrict__ ip,       // [64,8]
    const int*   __restrict__ port,     // [64,2]
    const float* __restrict__ hidden,   // [128]
    const float* __restrict__ ip_emb,   // [256,1]
    const float* __restrict__ port_emb, // [70000,4]
    const float* __restrict__ W_ih,     // [384,33] row-major
    const float* __restrict__ W_hh,     // [384,128] row-major
    const float* __restrict__ b_ih,     // [384]
    const float* __restrict__ b_hh,     // [384]
    float* __restrict__ out)            // [64*128 + 128]
{
    __shared__ float xi[F_IN];
    __shared__ float h0[H];

    const int s = blockIdx.x;   // step
    const int j = threadIdx.x;  // hidden unit

    // Stage xi = concat(x[s], ip_emb[ip[s]], port_emb[port[s]].flatten()) into LDS
    if (j < 17) {
        xi[j] = x[s * 17 + j];
    } else if (j < 25) {
        xi[j] = ip_emb[ip[s * 8 + (j - 17)]];
    } else if (j < F_IN) {
        int c = j - 25;                      // 0..7
        xi[j] = port_emb[port[s * 2 + (c >> 2)] * 4 + (c & 3)];
    }
    h0[j] = hidden[j];
    __syncthreads();

    // gh = h0 @ W_hh^T + b_hh  (rows j, j+H, j+2H)
    float ghr = b_hh[j];
    float ghz = b_hh[j + H];
    float ghn = b_hh[j + 2 * H];
    const float* wr = W_hh + (size_t)j * H;
    const float* wz = W_hh + (size_t)(j + H) * H;
    const float* wn = W_hh + (size_t)(j + 2 * H) * H;
    #pragma unroll 8
    for (int k = 0; k < H; ++k) {
        float h = h0[k];
        ghr = fmaf(h, wr[k], ghr);
        ghz = fmaf(h, wz[k], ghz);
        ghn = fmaf(h, wn[k], ghn);
    }

    // gi = xi @ W_ih^T + b_ih  (rows j, j+H, j+2H)
    float gir = b_ih[j];
    float giz = b_ih[j + H];
    float gin = b_ih[j + 2 * H];
    const float* vr = W_ih + (size_t)j * F_IN;
    const float* vz = W_ih + (size_t)(j + H) * F_IN;
    const float* vn = W_ih + (size_t)(j + 2 * H) * F_IN;
    #pragma unroll
    for (int k = 0; k < F_IN; ++k) {
        float xv = xi[k];
        gir = fmaf(xv, vr[k], gir);
        giz = fmaf(xv, vz[k], giz);
        gin = fmaf(xv, vn[k], gin);
    }

    float r = 1.0f / (1.0f + expf(-(gir + ghr)));
    float z = 1.0f / (1.0f + expf(-(giz + ghz)));
    float n = tanhf(gin + r * ghn);
    float o = (1.0f - z) * n + z * h0[j];

    out[s * H + j] = o;
    if (s == STEPS - 1) out[STEPS * H + j] = o;  // new_hidden tail
}

extern "C" void kernel_launch(void* const* d_in, const int* in_sizes, int n_in,
                              void* d_out, int out_size, void* d_ws, size_t ws_size,
                              hipStream_t stream) {
    const float* x        = (const float*)d_in[0];
    const int*   ip       = (const int*)  d_in[1];
    const int*   port     = (const int*)  d_in[2];
    const float* hidden   = (const float*)d_in[3];
    const float* ip_emb   = (const float*)d_in[4];
    const float* port_emb = (const float*)d_in[5];
    const float* W_ih     = (const float*)d_in[6];
    const float* W_hh     = (const float*)d_in[7];
    const float* b_ih     = (const float*)d_in[8];
    const float* b_hh     = (const float*)d_in[9];
    float* out = (float*)d_out;

    Encoder_57380763074770_kernel<<<STEPS, H, 0, stream>>>(
        x, ip, port, hidden, ip_emb, port_emb, W_ih, W_hh, b_ih, b_hh, out);
}